// Round 8
// baseline (112.027 us; speedup 1.0000x reference)
//
#include <hip/hip_runtime.h>
#include <hip/hip_bf16.h>

#define N2 16384
#define D  128
#define PANEL 16384                       // bytes per 128x128 fp8 panel
#define SQC1 1.69864360258810896f         // sqrt(2*log2(e)), folded into zq
#define LN2  0.69314718055994530942f

typedef float f32x4 __attribute__((ext_vector_type(4)));

#if __has_builtin(__builtin_amdgcn_exp2f)
#define EXP2(x) __builtin_amdgcn_exp2f(x)
#else
#define EXP2(x) exp2f(x)
#endif

// manual f32 -> OCP e4m3fn, RNE. |f| <= ~1.8 here (no overflow path).
__device__ __forceinline__ unsigned char f2e4m3(float f) {
    union { float f; unsigned u; } v; v.f = f;
    unsigned s = (v.u >> 24) & 0x80;
    int e = (int)((v.u >> 23) & 255) - 127;
    unsigned m = v.u & 0x7fffff;
    if (e < -10) return (unsigned char)s;           // underflows to +-0
    if (e >= -6) {                                  // normal e4m3
        unsigned r = m + 0x7ffff + ((m >> 20) & 1); // RNE on 3-bit mantissa
        unsigned mm = r >> 20;
        int E = e;
        if (mm >= 8) { mm = 0; E += 1; }            // mantissa carry
        return (unsigned char)(s | ((E + 7) << 3) | (mm & 7));
    }
    // subnormal: round(|f| * 2^9), n in [0,8]; n==8 naturally encodes 2^-6
    float a = fabsf(f) * 512.0f;
    int n = (int)rintf(a);
    return (unsigned char)(s | n);
}

// stage one 16KB fp8 panel global->LDS via global_load_lds width=16.
// LDS dest linear; XOR swizzle applied to the GLOBAL source (involution on
// 16B granules); reads use byte ^ ((row&7)<<4), row = byte>>7. (rule #21)
__device__ __forceinline__ void stage16(const char* __restrict__ g,
                                        char* lds, int tid) {
    const int wid = tid >> 6, lane = tid & 63;
    #pragma unroll
    for (int i = 0; i < 4; ++i) {
        int off = (wid << 12) + (i << 10) + (lane << 4);
        int src = off ^ (((off >> 7) & 7) << 4);
        __builtin_amdgcn_global_load_lds(
            (const __attribute__((address_space(1))) unsigned*)(g + src),
            (__attribute__((address_space(3))) unsigned*)(lds + (wid << 12) + (i << 10)),
            16, 0, 0);
    }
}

// ---------- kernel 1: L2-normalize -> fp8 sqrt(C1)*zn; zero rowsum/possum/out ----------
__global__ void k_norm(const float* __restrict__ z, unsigned char* __restrict__ zq,
                       float* __restrict__ rowsum, float* __restrict__ possum,
                       float* __restrict__ out) {
    if (blockIdx.x < 64) rowsum[blockIdx.x * 256 + threadIdx.x] = 0.f;
    if (blockIdx.x == 64 && threadIdx.x == 0) { out[0] = 0.f; possum[0] = 0.f; }
    int row  = blockIdx.x * 4 + (threadIdx.x >> 6);
    int lane = threadIdx.x & 63;
    const float2 v = ((const float2*)(z + (size_t)row * D))[lane];
    float ss = v.x * v.x + v.y * v.y;
    #pragma unroll
    for (int m = 1; m < 64; m <<= 1) ss += __shfl_xor(ss, m);
    float inv = SQC1 / fmaxf(sqrtf(ss), 1e-12f);
    unsigned short o = (unsigned short)f2e4m3(v.x * inv)
                     | ((unsigned short)f2e4m3(v.y * inv) << 8);
    ((unsigned short*)(zq + (size_t)row * D))[lane] = o;
}

// ---------- kernel 2: symmetric fused sim GEMM (fp8) + exp row/col sums ----------
// block (c, ti): s in [11c, min(11c+11,64)); c==5 adds s=64 when ti<64.
// jt=(ti+s)&127. A(ti) fp8 frags in regs; B panels dbuf'd in 2x16KB.
// Column-sum atomics pipelined 2-deep: tile t-1's flush issues after
// stage(t+1), so vmcnt(8) (4 stage + 4 atomics newer) drains stage(t)
// without waiting on fresh atomics. pos_sim extracted from diag tile.
__global__ __launch_bounds__(256, 3)
void k_sim(const unsigned char* __restrict__ zq, float* __restrict__ rowsum,
           float* __restrict__ possum) {
    __shared__ char ls[2 * PANEL];        // 32KB: A prologue via ls0, then B dbuf
    char* ls0 = ls;
    char* ls1 = ls + PANEL;

    const int tileI = blockIdx.y;
    const int c = blockIdx.x;
    const int sLo = c * 11;
    const int nt = (c < 5) ? 11 : ((tileI < 64) ? 10 : 9);

    const int tid  = threadIdx.x;
    const int lane = tid & 63, wid = tid >> 6;
    const int wr = wid >> 1, wc = wid & 1;          // 2x2 waves: 64x64 each
    const int l16 = lane & 15, lg = lane >> 4;
    const char* zb = (const char*)zq;

    // prologue: stage A(ti) -> ls0, pull A fragments (fp8 i64) to registers
    stage16(zb + (size_t)tileI * PANEL, ls0, tid);
    asm volatile("s_waitcnt vmcnt(0)" ::: "memory");
    __builtin_amdgcn_s_barrier();

    long af[4][4];                                     // [kk][m], 8 fp8 each
    #pragma unroll
    for (int kk = 0; kk < 4; ++kk)
        #pragma unroll
        for (int m = 0; m < 4; ++m) {
            int row = wr * 64 + m * 16 + l16;
            int d = row * 128 + kk * 32 + lg * 8;
            af[kk][m] = *(const long*)(ls0 + (d ^ ((row & 7) << 4)));
        }
    asm volatile("s_waitcnt lgkmcnt(0)" ::: "memory");
    __builtin_amdgcn_s_barrier();                      // ls0 free for B

    stage16(zb + (size_t)((tileI + sLo) & 127) * PANEL, ls0, tid);  // B(sLo)

    float rs[4][4];
    #pragma unroll
    for (int m = 0; m < 4; ++m)
        #pragma unroll
        for (int r = 0; r < 4; ++r) rs[m][r] = 0.f;
    float csp[4] = {0.f, 0.f, 0.f, 0.f};               // prev tile col sums
    int jtp = tileI;                                   // dummy (adds 0.0)

    for (int t = 0; t < nt; ++t) {
        const int s  = sLo + t;
        const int jt = (tileI + s) & 127;
        char* rbuf = (t & 1) ? ls1 : ls0;
        char* sbuf = (t & 1) ? ls0 : ls1;

        // a) prefetch next B panel (4 loads)
        if (t + 1 < nt)
            stage16(zb + (size_t)((tileI + s + 1) & 127) * PANEL, sbuf, tid);
        // b) flush PREVIOUS tile's column sums (4 atomics; 2-tile latency cover)
        #pragma unroll
        for (int n = 0; n < 4; ++n) {
            float v = csp[n];
            v += __shfl_xor(v, 16);
            v += __shfl_xor(v, 32);
            if (lg == 0)
                atomicAdd(&rowsum[jtp * 128 + wc * 64 + n * 16 + l16], v);
        }
        // c) stage(t) drained; 8 newer ops (4 stage + 4 atomics) stay in flight
        if (t + 1 < nt) { asm volatile("s_waitcnt vmcnt(8)" ::: "memory"); }
        else           { asm volatile("s_waitcnt vmcnt(4)" ::: "memory"); }
        __builtin_amdgcn_s_barrier();                  // stage(t) visible

        // e) K-loop: per-kk fragment reads (compiler-scheduled lgkm waits)
        f32x4 acc[4][4];
        #pragma unroll
        for (int m = 0; m < 4; ++m)
            #pragma unroll
            for (int n = 0; n < 4; ++n)
                acc[m][n] = f32x4{0.f, 0.f, 0.f, 0.f};
        #pragma unroll
        for (int kk = 0; kk < 4; ++kk) {
            long bk[4];
            #pragma unroll
            for (int n = 0; n < 4; ++n) {
                int row = wc * 64 + n * 16 + l16;
                int d = row * 128 + kk * 32 + lg * 8;
                bk[n] = *(const long*)(rbuf + (d ^ ((row & 7) << 4)));
            }
            #pragma unroll
            for (int m = 0; m < 4; ++m)
                #pragma unroll
                for (int n = 0; n < 4; ++n)
                    acc[m][n] = __builtin_amdgcn_mfma_f32_16x16x32_fp8_fp8(
                        af[kk][m], bk[n], acc[m][n], 0, 0, 0);
        }
        __builtin_amdgcn_s_barrier();                  // rbuf reads done -> reusable

        // g) epilogue: e = exp2(acc) = exp(sim)
        if (s == 0) {
            // diagonal tile: mask self, extract pos (j = i^1 lives here)
            float pp = 0.f;
            #pragma unroll
            for (int m = 0; m < 4; ++m)
                #pragma unroll
                for (int r = 0; r < 4; ++r) {
                    int li = wr * 64 + m * 16 + lg * 4 + r;
                    float a = 0.f;
                    #pragma unroll
                    for (int n = 0; n < 4; ++n) {
                        int lj = wc * 64 + n * 16 + l16;
                        float e = EXP2(acc[m][n][r]);
                        a += (li == lj) ? 0.f : e;
                    }
                    rs[m][r] += a;
                    // pos: same wave iff wc==wr; col block n==m; lane (lg*4+r)^1
                    if (wc == wr && l16 == ((lg * 4 + r) ^ 1))
                        pp += acc[m][m][r];
                }
            // wave-reduce pos partial, one atomic
            #pragma unroll
            for (int sh = 1; sh < 64; sh <<= 1) pp += __shfl_xor(pp, sh);
            if (lane == 0 && wc == wr) atomicAdd(possum, pp);
            csp[0] = csp[1] = csp[2] = csp[3] = 0.f;
            jtp = tileI;
        } else {
            float cs[4] = {0.f, 0.f, 0.f, 0.f};
            #pragma unroll
            for (int m = 0; m < 4; ++m)
                #pragma unroll
                for (int r = 0; r < 4; ++r) {
                    float a = 0.f;
                    #pragma unroll
                    for (int n = 0; n < 4; ++n) {
                        float e = EXP2(acc[m][n][r]);
                        a += e;
                        cs[n] += e;
                    }
                    rs[m][r] += a;
                }
            #pragma unroll
            for (int n = 0; n < 4; ++n) csp[n] = cs[n];
            jtp = jt;
        }
    }

    // final flush: last tile's column sums
    #pragma unroll
    for (int n = 0; n < 4; ++n) {
        float v = csp[n];
        v += __shfl_xor(v, 16);
        v += __shfl_xor(v, 32);
        if (lg == 0)
            atomicAdd(&rowsum[jtp * 128 + wc * 64 + n * 16 + l16], v);
    }
    // row sums: reduce across 16 column-lanes, one atomic per row
    #pragma unroll
    for (int m = 0; m < 4; ++m)
        #pragma unroll
        for (int r = 0; r < 4; ++r) {
            float v = rs[m][r];
            v += __shfl_xor(v, 1);
            v += __shfl_xor(v, 2);
            v += __shfl_xor(v, 4);
            v += __shfl_xor(v, 8);
            if (l16 == 0)
                atomicAdd(&rowsum[tileI * 128 + wr * 64 + m * 16 + lg * 4 + r], v);
        }
}

// ---------- kernel 3: loss mean = (1/N2)*[sum_i ln(rowsum_i) - ln2*possum] ----------
__global__ void k_loss_reduce(const float* __restrict__ rowsum,
                              const float* __restrict__ possum,
                              float* __restrict__ out) {
    const int tid = threadIdx.x + blockIdx.x * 256;   // 64 blocks x 256
    float part = logf(rowsum[tid]);
    __shared__ float sm[4];
    #pragma unroll
    for (int m = 1; m < 64; m <<= 1) part += __shfl_xor(part, m);
    if ((threadIdx.x & 63) == 0) sm[threadIdx.x >> 6] = part;
    __syncthreads();
    if (threadIdx.x == 0) {
        float v = sm[0] + sm[1] + sm[2] + sm[3];
        if (blockIdx.x == 0) v -= LN2 * possum[0];    // pos term (log2->ln units)
        atomicAdd(out, v * (1.0f / (float)N2));
    }
}

extern "C" void kernel_launch(void* const* d_in, const int* in_sizes, int n_in,
                              void* d_out, int out_size, void* d_ws, size_t ws_size,
                              hipStream_t stream) {
    const float* z = (const float*)d_in[0];
    float* out = (float*)d_out;

    unsigned char* zq = (unsigned char*)d_ws;                         // 2 MiB fp8
    float* rowsum = (float*)((char*)d_ws + (size_t)N2 * D);           // 64 KiB
    float* possum = rowsum + N2;                                      // 4 B

    k_norm<<<N2 / 4, 256, 0, stream>>>(z, zq, rowsum, possum, out);
    dim3 grid(6, 128);                                                // s-chunks x i-tiles
    k_sim<<<grid, 256, 0, stream>>>(zq, rowsum, possum);
    k_loss_reduce<<<64, 256, 0, stream>>>(rowsum, possum, out);
}